// Round 11
// baseline (154.482 us; speedup 1.0000x reference)
//
#include <hip/hip_runtime.h>
#include <math.h>

#define BATCH 32
#define HH 512
#define WW 512
#define NC 32        // cells per side
#define NORI 6
#define CH 262144    // HH*WW channel stride (floats)

// ---- round-5-verbatim numpy downstream (cold path, ONE inline copy) ----
__device__ __forceinline__ int bin_of(float a) {
    const float deg = __fmul_rn(a, 57.29577951308232f);
    float m = fmodf(deg, 180.0f);
    if (m < 0.0f) m = __fadd_rn(m, 180.0f);
    const int b = (int)floorf(__fdiv_rn(m, 30.0f));
    return min(max(b, 0), NORI - 1);
}
__device__ __forceinline__ float ulp_step(float x, int k) {
    const int i = __float_as_int(x);
    int key = (i >= 0) ? i : -(i & 0x7FFFFFFF);
    key += k;
    const int r = (key >= 0) ? key : (int)(0x80000000u | (unsigned)(-key));
    return __int_as_float(r);
}
__device__ __forceinline__ void deposit(float acc[NORI], int bin, float val) {
#pragma unroll
    for (int o = 0; o < NORI; ++o) acc[o] += (bin == o) ? val : 0.0f;
}
// (0.299*R + 0.587*G) + 0.114*B, f32, no FMA contraction
__device__ __forceinline__ float gray_comb(float r, float g, float b) {
    return __fadd_rn(__fadd_rn(__fmul_rn(0.299f, r), __fmul_rn(0.587f, g)),
                     __fmul_rn(0.114f, b));
}
__device__ __forceinline__ float gray_i(const float* __restrict__ img, int off) {
    return gray_comb(img[off], img[off + CH], img[off + 2 * CH]);
}

__device__ __forceinline__ void hot_pixel(float gy, float gx, int bitk,
                                          float acc[NORI], unsigned& ambmask) {
    const float mag = __fsqrt_rn(__fmaf_rn(gy, gy, __fmul_rn(gx, gx)));
    // canonicalize to theta in [0,180)
    const bool neg = gy < 0.0f;
    const float cy = fabsf(gy);
    const float cx = neg ? -gx : gx;
    // t_i ~ sin(theta - alpha_i), alpha = 30,60,90,120,150 (shared products)
    const float pa = __fmul_rn(cy, 0.86602540378443864676f);
    const float pb = __fmul_rn(cx, 0.5f);
    const float pc = __fmul_rn(cy, 0.5f);
    const float pd = __fmul_rn(cx, 0.86602540378443864676f);
    const float t1 = __fsub_rn(pa, pb);
    const float t2 = __fsub_rn(pc, pd);
    const float t3 = -cx;
    const float t4 = -__fadd_rn(pc, pd);
    const float t5 = -__fadd_rn(pa, pb);
    int bin = (t1 >= 0.0f) + (t2 >= 0.0f) + (t3 >= 0.0f) +
              (t4 >= 0.0f) + (t5 >= 0.0f);
    const float s = __fmul_rn(mag, 1e-5f);
    const float mn = fminf(fminf(fminf(fabsf(t1), fabsf(t2)),
                                 fminf(fabsf(t3), fabsf(t4))), fabsf(t5));
    bool amb = (mn < s) || (cx < 0.0f && cy < s);   // incl. wrap at 180
    if (gy == 0.0f) { bin = 0; amb = false; }       // deterministic (r3/r5)
    else if (gx == 0.0f) { bin = 3; amb = false; }
    ambmask |= amb ? (1u << bitk) : 0u;
    deposit(acc, bin, amb ? 0.0f : mag);
}

// Lane = 4 adjacent columns; wave = 256 cols x 4 output rows; block = 4 waves
// = one 16-row cell-row x 256 cols. ALL 18 channel loads (6 rows x 3 ch,
// dwordx4) are issued back-to-back before any compute -> ~18 KB/wave in
// flight (vs 3 KB rolling-window) to break the memory-latency / Little's-law
// ceiling seen in r6-r10. Classifier + cold path + epilogue are r10-verbatim.
__global__ __launch_bounds__(256) void hog_cells_kernel(const float* __restrict__ x,
                                                        float* __restrict__ cells) {
    const int b = blockIdx.z;
    const int tid = threadIdx.x;
    const int wave = tid >> 6, lane = tid & 63;
    const int by = blockIdx.y;              // cell row
    const int R0 = by * 16 + wave * 4;      // this wave's first output row
    const int C0 = blockIdx.x * 256;
    const int c0 = C0 + lane * 4;
    const float* img = x + (size_t)b * 3 * HH * WW;

    __shared__ float hist[16][NORI];
    if (tid < 16 * NORI) ((float*)hist)[tid] = 0.0f;
    __syncthreads();

    // single halo column per wave: left block needs abs col 256 (lane 63),
    // right block needs abs col 255 (lane 0). Image borders give gx=0 instead.
    const bool left_blk = (blockIdx.x == 0);
    const int hc = left_blk ? 256 : 255;
    const bool is_h = (lane == (left_blk ? 63 : 0));

    // window rows R0-1 .. R0+4, clamped (row_ok gates the clamped ones)
    int roff[6];
#pragma unroll
    for (int i = 0; i < 6; ++i)
        roff[i] = min(max(R0 - 1 + i, 0), HH - 1) * WW;

    // ---- burst-issue ALL loads (18 x dwordx4/wave, no data deps) ----
    float4 cr[6], cg[6], cb[6];
#pragma unroll
    for (int i = 0; i < 6; ++i) {
        cr[i] = *(const float4*)(img + roff[i] + c0);
        cg[i] = *(const float4*)(img + roff[i] + c0 + CH);
        cb[i] = *(const float4*)(img + roff[i] + c0 + 2 * CH);
    }
    float hrow[6];
#pragma unroll
    for (int i = 0; i < 6; ++i)
        hrow[i] = is_h ? gray_i(img, roff[i] + hc) : 0.0f;

    // ---- gray conversion (retires cr/cg/cb as it goes) ----
    float4 g[6];
#pragma unroll
    for (int i = 0; i < 6; ++i) {
        g[i].x = gray_comb(cr[i].x, cg[i].x, cb[i].x);
        g[i].y = gray_comb(cr[i].y, cg[i].y, cb[i].y);
        g[i].z = gray_comb(cr[i].z, cg[i].z, cb[i].z);
        g[i].w = gray_comb(cr[i].w, cg[i].w, cb[i].w);
    }

    float acc[NORI] = {0, 0, 0, 0, 0, 0};
    unsigned ambmask = 0;

#pragma unroll
    for (int k = 0; k < 4; ++k) {
        const int r = R0 + k;
        const bool row_ok = (r >= 1) && (r < HH - 1);
        const float4 gt = g[k], gc = g[k + 1], gb = g[k + 2];
        const float gy0 = row_ok ? __fsub_rn(gb.x, gt.x) : 0.0f;
        const float gy1 = row_ok ? __fsub_rn(gb.y, gt.y) : 0.0f;
        const float gy2 = row_ok ? __fsub_rn(gb.z, gt.z) : 0.0f;
        const float gy3 = row_ok ? __fsub_rn(gb.w, gt.w) : 0.0f;

        float left  = __shfl(gc.w, (lane + 63) & 63);
        float right = __shfl(gc.x, (lane + 1) & 63);
        if (is_h) { if (left_blk) right = hrow[k + 1]; else left = hrow[k + 1]; }

        float gx0 = __fsub_rn(gc.y, left);
        const float gx1 = __fsub_rn(gc.z, gc.x);
        const float gx2 = __fsub_rn(gc.w, gc.y);
        float gx3 = __fsub_rn(right, gc.z);
        if (c0 == 0) gx0 = 0.0f;             // image left border
        if (c0 + 3 == WW - 1) gx3 = 0.0f;    // image right border

        hot_pixel(gy0, gx0, 4 * k + 0, acc, ambmask);
        hot_pixel(gy1, gx1, 4 * k + 1, acc, ambmask);
        hot_pixel(gy2, gx2, 4 * k + 2, acc, ambmask);
        hot_pixel(gy3, gx3, 4 * k + 3, acc, ambmask);
    }

    // cold phase: rare. amb pixels are interior with gy!=0 && gx!=0;
    // recompute bitwise-identically from global memory.
    if (__any(ambmask != 0)) {
        unsigned m = ambmask;
        while (m) {
            const int bit = __builtin_ctz(m);
            m &= m - 1;
            const int r = R0 + (bit >> 2);
            const int c = c0 + (bit & 3);
            const int off = r * WW + c;
            const float gy = __fsub_rn(gray_i(img, off + WW), gray_i(img, off - WW));
            const float gx = __fsub_rn(gray_i(img, off + 1), gray_i(img, off - 1));
            const float mag = __fsqrt_rn(__fmaf_rn(gy, gy, __fmul_rn(gx, gx)));
            const float a = atan2f(gy, gx);
            const int bl = bin_of(ulp_step(a, -2));
            const int bh = bin_of(ulp_step(a, +2));
            if (bl == bh) {
                deposit(acc, bl, mag);
            } else {
                const int b0 = bin_of(a);
                const int bo = (b0 == bl) ? bh : bl;
                deposit(acc, b0, __fmul_rn(mag, 0.65f));
                deposit(acc, bo, __fmul_rn(mag, 0.35f));
            }
        }
    }

    // reduce the 4 lanes of each cell (16 cols = lanes 4c..4c+3)
#pragma unroll
    for (int o = 0; o < NORI; ++o) {
        float v = acc[o];
        v += __shfl_xor(v, 1);
        v += __shfl_xor(v, 2);
        acc[o] = v;
    }
    if ((lane & 3) == 0) {
        const int cell = lane >> 2;
#pragma unroll
        for (int o = 0; o < NORI; ++o) atomicAdd(&hist[cell][o], acc[o]);
    }
    __syncthreads();
    if (tid < 96) {
        const int cell = tid / 6, o = tid - cell * 6;
        cells[(((size_t)b * NC + by) * NC + ((C0 >> 4) + cell)) * NORI + o] =
            hist[cell][o] * (1.0f / 256.0f);
    }
}

// One thread per (b, block_row, block_col): float2 loads, L2-Hys normalize.
__global__ __launch_bounds__(256) void hog_norm_kernel(const float* __restrict__ cells,
                                                       float* __restrict__ out) {
    const int idx = blockIdx.x * 256 + threadIdx.x;
    const int total = BATCH * 31 * 31;
    if (idx >= total) return;
    const int bc = idx % 31;
    const int t = idx / 31;
    const int br = t % 31;
    const int b = t / 31;

    const float* cb = cells + (size_t)b * NC * NC * NORI;
    const float2* p0 = (const float2*)(cb + ((br) * NC + bc) * NORI);
    const float2* p1 = (const float2*)(cb + ((br + 1) * NC + bc) * NORI);
    float v[24];
#pragma unroll
    for (int q = 0; q < 6; ++q) {
        const float2 r0 = p0[q], r1 = p1[q];
        v[2 * q] = r0.x; v[2 * q + 1] = r0.y;
        v[12 + 2 * q] = r1.x; v[12 + 2 * q + 1] = r1.y;
    }
    float ss = 0.0f;
#pragma unroll
    for (int k = 0; k < 24; ++k) ss = __fadd_rn(ss, __fmul_rn(v[k], v[k]));
    const float n1 = __fsqrt_rn(__fadd_rn(ss, 1e-10f));  // EPS^2, EPS=1e-5
    float ss2 = 0.0f;
#pragma unroll
    for (int k = 0; k < 24; ++k) {
        v[k] = fminf(__fdiv_rn(v[k], n1), 0.2f);
        ss2 = __fadd_rn(ss2, __fmul_rn(v[k], v[k]));
    }
    const float n2 = __fsqrt_rn(__fadd_rn(ss2, 1e-10f));
    float* op = out + (size_t)idx * 24;
#pragma unroll
    for (int k = 0; k < 24; ++k) op[k] = __fdiv_rn(v[k], n2);
}

extern "C" void kernel_launch(void* const* d_in, const int* in_sizes, int n_in,
                              void* d_out, int out_size, void* d_ws, size_t ws_size,
                              hipStream_t stream) {
    const float* x = (const float*)d_in[0];
    float* out = (float*)d_out;
    float* cells = (float*)d_ws;  // BATCH*32*32*6 floats = 3 MB

    dim3 g1(2, NC, BATCH), b1(256);
    hog_cells_kernel<<<g1, b1, 0, stream>>>(x, cells);

    const int total = BATCH * 31 * 31;
    hog_norm_kernel<<<(total + 255) / 256, 256, 0, stream>>>(cells, out);
}